// Round 1
// baseline (2456.471 us; speedup 1.0000x reference)
//
#include <hip/hip_runtime.h>

#define HIDF 128

static inline int cdiv(int a, int b) { return (a + b - 1) / b; }

// ---- degree count over dst ----
__global__ void k_deg(const int* __restrict__ dst, int E, int* __restrict__ deg) {
    int i = blockIdx.x * blockDim.x + threadIdx.x;
    if (i < E) atomicAdd(&deg[dst[i]], 1);
}

// ---- dinv = rsqrt(max(deg,1)) ----
__global__ void k_dinv(const int* __restrict__ deg, int N, float* __restrict__ dinv) {
    int i = blockIdx.x * blockDim.x + threadIdx.x;
    if (i < N) {
        float d = (float)deg[i];
        dinv[i] = rsqrtf(fmaxf(d, 1.0f));
    }
}

// ---- single-block exclusive scan deg -> row_ptr (N+1 entries) ----
__global__ __launch_bounds__(1024) void k_scan(const int* __restrict__ deg, int N,
                                               int* __restrict__ row_ptr) {
    __shared__ int ls[1024];
    int tid = threadIdx.x;
    int chunk = (N + 1023) / 1024;
    int start = tid * chunk;
    int end = min(start + chunk, N);
    int s = 0;
    for (int i = start; i < end; ++i) s += deg[i];
    ls[tid] = s;
    __syncthreads();
    for (int off = 1; off < 1024; off <<= 1) {
        int v = (tid >= off) ? ls[tid - off] : 0;
        __syncthreads();
        ls[tid] += v;
        __syncthreads();
    }
    int run = ls[tid] - s;  // exclusive prefix
    for (int i = start; i < end; ++i) {
        row_ptr[i] = run;
        run += deg[i];
    }
    if (tid == 1023) row_ptr[N] = run;
}

// ---- scatter edges into CSR (by dst) ----
__global__ void k_scatter(const int* __restrict__ src, const int* __restrict__ dst, int E,
                          const int* __restrict__ row_ptr, int* __restrict__ fill,
                          const float* __restrict__ dinv, int* __restrict__ csr_src,
                          float* __restrict__ csr_w) {
    int i = blockIdx.x * blockDim.x + threadIdx.x;
    if (i < E) {
        int s = src[i], d = dst[i];
        int pos = row_ptr[d] + atomicAdd(&fill[d], 1);
        csr_src[pos] = s;
        csr_w[pos] = dinv[s] * dinv[d];
    }
}

// ---- input GEMM: H = X @ W + b,  X:[M,Kdim], W:[Kdim,128] ----
// BM=64, BN=128, BK=20, 256 threads, each computes 8x4
__global__ __launch_bounds__(256) void k_gemm_in(const float* __restrict__ X,
                                                 const float* __restrict__ W,
                                                 const float* __restrict__ b,
                                                 float* __restrict__ H, int M, int Kdim) {
    const int BK = 20;
    __shared__ float As[64][BK + 1];
    __shared__ float Bs[BK][128];
    int tid = threadIdx.x;
    int tx = tid & 31, ty = tid >> 5;
    int row0 = blockIdx.x * 64;
    float acc[8][4] = {};
    for (int k0 = 0; k0 < Kdim; k0 += BK) {
        for (int l = tid; l < 64 * BK; l += 256) {
            int m = l / BK, k = l % BK;
            int r = row0 + m;
            As[m][k] = (r < M) ? X[(long)r * Kdim + k0 + k] : 0.0f;
        }
        for (int l = tid; l < BK * 128; l += 256) {
            int k = l >> 7, n = l & 127;
            Bs[k][n] = W[(long)(k0 + k) * 128 + n];
        }
        __syncthreads();
#pragma unroll
        for (int k = 0; k < BK; ++k) {
            float a[8], bb[4];
#pragma unroll
            for (int i = 0; i < 8; ++i) a[i] = As[ty * 8 + i][k];
#pragma unroll
            for (int j = 0; j < 4; ++j) bb[j] = Bs[k][tx * 4 + j];
#pragma unroll
            for (int i = 0; i < 8; ++i)
#pragma unroll
                for (int j = 0; j < 4; ++j) acc[i][j] += a[i] * bb[j];
        }
        __syncthreads();
    }
#pragma unroll
    for (int i = 0; i < 8; ++i) {
        int r = row0 + ty * 8 + i;
        if (r < M) {
#pragma unroll
            for (int j = 0; j < 4; ++j) {
                int n = tx * 4 + j;
                H[(long)r * 128 + n] = acc[i][j] + b[n];
            }
        }
    }
}

// ---- fused prop step: acc (+)= g*t_in ; t_out = high ? t_in - P t_in : P t_in ----
// one wave per node, 2 features per lane
__global__ __launch_bounds__(256) void k_prop(const int* __restrict__ row_ptr,
                                              const int* __restrict__ csr_src,
                                              const float* __restrict__ csr_w,
                                              const float* __restrict__ t_in,
                                              float* __restrict__ t_out,
                                              float* __restrict__ acc,
                                              const float* __restrict__ gamma, int kidx, int N,
                                              int high, int first, int do_prop) {
    int wave = threadIdx.x >> 6;
    int lane = threadIdx.x & 63;
    int node = blockIdx.x * (blockDim.x >> 6) + wave;
    if (node >= N) return;
    float g = gamma[kidx];
    long base = (long)node * HIDF;
    float tv0 = t_in[base + lane];
    float tv1 = t_in[base + lane + 64];
    float a0 = 0.f, a1 = 0.f;
    if (!first) {
        a0 = acc[base + lane];
        a1 = acc[base + lane + 64];
    }
    acc[base + lane] = a0 + g * tv0;
    acc[base + lane + 64] = a1 + g * tv1;
    if (do_prop) {
        int e0 = row_ptr[node], e1 = row_ptr[node + 1];
        float s0 = 0.f, s1 = 0.f;
        for (int e = e0; e < e1; ++e) {
            int s = csr_src[e];
            float w = csr_w[e];
            long sb = (long)s * HIDF;
            s0 += w * t_in[sb + lane];
            s1 += w * t_in[sb + lane + 64];
        }
        t_out[base + lane] = high ? (tv0 - s0) : s0;
        t_out[base + lane + 64] = high ? (tv1 - s1) : s1;
    }
}

// ---- BN stats: per-column sum / sumsq with block-partial + atomics ----
__global__ __launch_bounds__(256) void k_stats(const float* __restrict__ acc, int N,
                                               float* __restrict__ sums) {
    int tid = threadIdx.x;
    int f = tid & 127;
    int g = tid >> 7;
    float s1 = 0.f, s2 = 0.f;
    for (int r = blockIdx.x * 2 + g; r < N; r += gridDim.x * 2) {
        float v = acc[(long)r * HIDF + f];
        s1 += v;
        s2 += v * v;
    }
    __shared__ float l1[256], l2[256];
    l1[tid] = s1;
    l2[tid] = s2;
    __syncthreads();
    if (tid < 128) {
        atomicAdd(&sums[f], l1[tid] + l1[tid + 128]);
        atomicAdd(&sums[128 + f], l2[tid] + l2[tid + 128]);
    }
}

// ---- finalize BN affine: a_mul/a_add per column ----
__global__ void k_bnfin(const float* __restrict__ sums, int N, const float* __restrict__ scale,
                        const float* __restrict__ shift, float* __restrict__ a_mul,
                        float* __restrict__ a_add) {
    int f = threadIdx.x;
    float mu = sums[f] / (float)N;
    float var = sums[128 + f] / (float)N - mu * mu;
    float rstd = rsqrtf(var + 1e-5f);
    float am = rstd * scale[f];
    a_mul[f] = am;
    a_add[f] = shift[f] - mu * am;
}

// ---- up GEMM with fused BN transform + bias + relu. A:[M,128], W:[128,128] ----
__global__ __launch_bounds__(256) void k_gemm_up(const float* __restrict__ A,
                                                 const float* __restrict__ W,
                                                 const float* __restrict__ bias,
                                                 const float* __restrict__ a_mul,
                                                 const float* __restrict__ a_add,
                                                 float* __restrict__ out, int M) {
    __shared__ float As[64][17];
    __shared__ float Bs[16][128];
    int tid = threadIdx.x;
    int tx = tid & 31, ty = tid >> 5;
    int row0 = blockIdx.x * 64;
    float acc[8][4] = {};
    for (int k0 = 0; k0 < 128; k0 += 16) {
        for (int l = tid; l < 64 * 16; l += 256) {
            int m = l >> 4, k = l & 15;
            int r = row0 + m;
            float v = (r < M) ? A[(long)r * 128 + k0 + k] : 0.0f;
            As[m][k] = v * a_mul[k0 + k] + a_add[k0 + k];
        }
        for (int l = tid; l < 16 * 128; l += 256) {
            int k = l >> 7, n = l & 127;
            Bs[k][n] = W[(long)(k0 + k) * 128 + n];
        }
        __syncthreads();
#pragma unroll
        for (int k = 0; k < 16; ++k) {
            float a[8], bb[4];
#pragma unroll
            for (int i = 0; i < 8; ++i) a[i] = As[ty * 8 + i][k];
#pragma unroll
            for (int j = 0; j < 4; ++j) bb[j] = Bs[k][tx * 4 + j];
#pragma unroll
            for (int i = 0; i < 8; ++i)
#pragma unroll
                for (int j = 0; j < 4; ++j) acc[i][j] += a[i] * bb[j];
        }
        __syncthreads();
    }
#pragma unroll
    for (int i = 0; i < 8; ++i) {
        int r = row0 + ty * 8 + i;
        if (r < M) {
#pragma unroll
            for (int j = 0; j < 4; ++j) {
                int n = tx * 4 + j;
                out[(long)r * 128 + n] = fmaxf(acc[i][j] + bias[n], 0.0f);
            }
        }
    }
}

extern "C" void kernel_launch(void* const* d_in, const int* in_sizes, int n_in, void* d_out,
                              int out_size, void* d_ws, size_t ws_size, hipStream_t stream) {
    const float* x = (const float*)d_in[0];
    const int* edge_index = (const int*)d_in[1];
    const float* W_in = (const float*)d_in[2];
    const float* b_in = (const float*)d_in[3];
    const float* gamma_L = (const float*)d_in[4];
    const float* gamma_H = (const float*)d_in[5];
    const float* bn_scale = (const float*)d_in[6];
    const float* bn_shift = (const float*)d_in[7];
    const float* W_up = (const float*)d_in[8];
    const float* b_up = (const float*)d_in[9];
    float* out = (float*)d_out;

    const int HID = in_sizes[3];      // 128
    const int IN = in_sizes[2] / HID; // 500
    const int N = in_sizes[0] / IN;   // 50000
    const int E = in_sizes[1] / 2;    // 800000
    const int K = in_sizes[4] - 1;    // 10

    const int* src = edge_index;
    const int* dst = edge_index + E;

    // workspace carve-out
    char* p = (char*)d_ws;
    auto alloc = [&](size_t bytes) -> void* {
        void* r = (void*)p;
        p += (bytes + 255) & ~(size_t)255;
        return r;
    };
    int* deg = (int*)alloc((size_t)N * 4);
    int* row_ptr = (int*)alloc((size_t)(N + 1) * 4);
    int* fill = (int*)alloc((size_t)N * 4);
    float* dinv = (float*)alloc((size_t)N * 4);
    int* csr_src = (int*)alloc((size_t)E * 4);
    float* csr_w = (float*)alloc((size_t)E * 4);
    float* h = (float*)alloc((size_t)N * HID * 4);
    float* ta = (float*)alloc((size_t)N * HID * 4);
    float* tb = (float*)alloc((size_t)N * HID * 4);
    float* accb = (float*)alloc((size_t)N * HID * 4);
    float* sums = (float*)alloc(256 * 4);
    float* a_mul = (float*)alloc(128 * 4);
    float* a_add = (float*)alloc(128 * 4);

    hipMemsetAsync(deg, 0, (size_t)N * 4, stream);
    hipMemsetAsync(fill, 0, (size_t)N * 4, stream);

    k_deg<<<cdiv(E, 256), 256, 0, stream>>>(dst, E, deg);
    k_dinv<<<cdiv(N, 256), 256, 0, stream>>>(deg, N, dinv);
    k_scan<<<1, 1024, 0, stream>>>(deg, N, row_ptr);
    k_scatter<<<cdiv(E, 256), 256, 0, stream>>>(src, dst, E, row_ptr, fill, dinv, csr_src,
                                                csr_w);
    k_gemm_in<<<cdiv(N, 64), 256, 0, stream>>>(x, W_in, b_in, h, N, IN);

    for (int enc = 0; enc < 2; ++enc) {
        const float* gam = enc ? gamma_H : gamma_L;
        int high = enc;
        hipMemsetAsync(sums, 0, 256 * 4, stream);
        const float* tin = h;
        float* tout = ta;
        for (int k = 0; k < K; ++k) {
            k_prop<<<cdiv(N, 4), 256, 0, stream>>>(row_ptr, csr_src, csr_w, tin, tout, accb,
                                                   gam, k, N, high, k == 0 ? 1 : 0, 1);
            tin = tout;
            tout = (tout == ta) ? tb : ta;
        }
        // last term: acc += g_K * t_K (no prop)
        k_prop<<<cdiv(N, 4), 256, 0, stream>>>(row_ptr, csr_src, csr_w, tin, tout, accb, gam,
                                               K, N, high, K == 0 ? 1 : 0, 0);
        k_stats<<<400, 256, 0, stream>>>(accb, N, sums);
        k_bnfin<<<1, 128, 0, stream>>>(sums, N, bn_scale, bn_shift, a_mul, a_add);
        k_gemm_up<<<cdiv(N, 64), 256, 0, stream>>>(accb, W_up, b_up, a_mul, a_add,
                                                   out + (size_t)enc * N * HID, N);
    }
}

// Round 2
// 1358.348 us; speedup vs baseline: 1.8084x; 1.8084x over previous
//
#include <hip/hip_runtime.h>

#define HIDF 128

static inline int cdiv(int a, int b) { return (a + b - 1) / b; }

// ---- degree count over dst ----
__global__ void k_deg(const int* __restrict__ dst, int E, int* __restrict__ deg) {
    int i = blockIdx.x * blockDim.x + threadIdx.x;
    if (i < E) atomicAdd(&deg[dst[i]], 1);
}

// ---- dinv = rsqrt(max(deg,1)) ----
__global__ void k_dinv(const int* __restrict__ deg, int N, float* __restrict__ dinv) {
    int i = blockIdx.x * blockDim.x + threadIdx.x;
    if (i < N) {
        float d = (float)deg[i];
        dinv[i] = rsqrtf(fmaxf(d, 1.0f));
    }
}

// ---- coefficient kernel: cL[j]=gamma_L[j]; cH[j]=(-1)^j sum_{k>=j} gamma_H[k]*C(k,j) ----
__global__ void k_coef(const float* __restrict__ gL, const float* __restrict__ gH, int K,
                       float* __restrict__ cL, float* __restrict__ cH) {
    if (threadIdx.x == 0 && blockIdx.x == 0) {
        for (int j = 0; j <= K; ++j) {
            double s = 0.0;
            double C = 1.0;  // C(j,j)
            for (int k = j; k <= K; ++k) {
                s += (double)gH[k] * C;
                C = C * (double)(k + 1) / (double)(k + 1 - j);  // C(k+1,j)
            }
            cH[j] = (j & 1) ? (float)(-s) : (float)s;
            cL[j] = gL[j];
        }
    }
}

// ---- single-block exclusive scan deg -> row_ptr (N+1 entries) ----
__global__ __launch_bounds__(1024) void k_scan(const int* __restrict__ deg, int N,
                                               int* __restrict__ row_ptr) {
    __shared__ int ls[1024];
    int tid = threadIdx.x;
    int chunk = (N + 1023) / 1024;
    int start = tid * chunk;
    int end = min(start + chunk, N);
    int s = 0;
    for (int i = start; i < end; ++i) s += deg[i];
    ls[tid] = s;
    __syncthreads();
    for (int off = 1; off < 1024; off <<= 1) {
        int v = (tid >= off) ? ls[tid - off] : 0;
        __syncthreads();
        ls[tid] += v;
        __syncthreads();
    }
    int run = ls[tid] - s;  // exclusive prefix
    for (int i = start; i < end; ++i) {
        row_ptr[i] = run;
        run += deg[i];
    }
    if (tid == 1023) row_ptr[N] = run;
}

// ---- scatter edges into CSR (by dst) ----
__global__ void k_scatter(const int* __restrict__ src, const int* __restrict__ dst, int E,
                          const int* __restrict__ row_ptr, int* __restrict__ fill,
                          const float* __restrict__ dinv, int* __restrict__ csr_src,
                          float* __restrict__ csr_w) {
    int i = blockIdx.x * blockDim.x + threadIdx.x;
    if (i < E) {
        int s = src[i], d = dst[i];
        int pos = row_ptr[d] + atomicAdd(&fill[d], 1);
        csr_src[pos] = s;
        csr_w[pos] = dinv[s] * dinv[d];
    }
}

// ---- input GEMM: H = X @ W + b; epilogue: accL = cL0*H, accH = cH0*H ----
// BM=64, BN=128, BK=20, 256 threads, each computes 8x4
__global__ __launch_bounds__(256) void k_gemm_in(
    const float* __restrict__ X, const float* __restrict__ W, const float* __restrict__ b,
    float* __restrict__ H, float* __restrict__ accL, float* __restrict__ accH,
    const float* __restrict__ cL, const float* __restrict__ cH, int M, int Kdim) {
    const int BK = 20;
    __shared__ float As[64][BK + 1];
    __shared__ float Bs[BK][128];
    int tid = threadIdx.x;
    int tx = tid & 31, ty = tid >> 5;
    int row0 = blockIdx.x * 64;
    float acc[8][4] = {};
    for (int k0 = 0; k0 < Kdim; k0 += BK) {
        for (int l = tid; l < 64 * BK; l += 256) {
            int m = l / BK, k = l % BK;
            int r = row0 + m;
            As[m][k] = (r < M) ? X[(long)r * Kdim + k0 + k] : 0.0f;
        }
        for (int l = tid; l < BK * 128; l += 256) {
            int k = l >> 7, n = l & 127;
            Bs[k][n] = W[(long)(k0 + k) * 128 + n];
        }
        __syncthreads();
#pragma unroll
        for (int k = 0; k < BK; ++k) {
            float a[8];
#pragma unroll
            for (int i = 0; i < 8; ++i) a[i] = As[ty * 8 + i][k];
            float4 bb = *(const float4*)&Bs[k][tx * 4];
#pragma unroll
            for (int i = 0; i < 8; ++i) {
                acc[i][0] += a[i] * bb.x;
                acc[i][1] += a[i] * bb.y;
                acc[i][2] += a[i] * bb.z;
                acc[i][3] += a[i] * bb.w;
            }
        }
        __syncthreads();
    }
    float g0 = cL[0], h0 = cH[0];
#pragma unroll
    for (int i = 0; i < 8; ++i) {
        int r = row0 + ty * 8 + i;
        if (r < M) {
#pragma unroll
            for (int j = 0; j < 4; ++j) {
                int n = tx * 4 + j;
                float v = acc[i][j] + b[n];
                long idx = (long)r * 128 + n;
                H[idx] = v;
                accL[idx] = g0 * v;
                accH[idx] = h0 * v;
            }
        }
    }
}

// ---- prop step j: t_out = P t_in ; accL += cL[j]*t_out ; accH += cH[j]*t_out ----
// one wave per node, float2 per lane (lane covers features 2*lane, 2*lane+1)
__global__ __launch_bounds__(256) void k_prop(
    const int* __restrict__ row_ptr, const int* __restrict__ csr_src,
    const float* __restrict__ csr_w, const float* __restrict__ t_in,
    float* __restrict__ t_out, float* __restrict__ accL, float* __restrict__ accH,
    const float* __restrict__ cL, const float* __restrict__ cH, int j, int N, int write_t) {
    int wave = threadIdx.x >> 6;
    int lane = threadIdx.x & 63;
    int node = blockIdx.x * 4 + wave;
    if (node >= N) return;
    float gL = cL[j], gH = cH[j];
    int e0 = row_ptr[node], e1 = row_ptr[node + 1];
    float sx = 0.f, sy = 0.f;
    int e = e0;
    for (; e + 2 <= e1; e += 2) {
        int i0 = csr_src[e], i1 = csr_src[e + 1];
        float w0 = csr_w[e], w1 = csr_w[e + 1];
        float2 v0 = *(const float2*)&t_in[(long)i0 * HIDF + lane * 2];
        float2 v1 = *(const float2*)&t_in[(long)i1 * HIDF + lane * 2];
        sx += w0 * v0.x;
        sy += w0 * v0.y;
        sx += w1 * v1.x;
        sy += w1 * v1.y;
    }
    if (e < e1) {
        int i0 = csr_src[e];
        float w0 = csr_w[e];
        float2 v0 = *(const float2*)&t_in[(long)i0 * HIDF + lane * 2];
        sx += w0 * v0.x;
        sy += w0 * v0.y;
    }
    long base = (long)node * HIDF + lane * 2;
    if (write_t) {
        float2 o = {sx, sy};
        *(float2*)&t_out[base] = o;
    }
    float2 aL = *(const float2*)&accL[base];
    float2 aH = *(const float2*)&accH[base];
    aL.x += gL * sx;
    aL.y += gL * sy;
    aH.x += gH * sx;
    aH.y += gH * sy;
    *(float2*)&accL[base] = aL;
    *(float2*)&accH[base] = aH;
}

// ---- BN stats for BOTH accs: per-column sum / sumsq ----
// sums layout: [0:128) L sum, [128:256) L sumsq, [256:384) H sum, [384:512) H sumsq
__global__ __launch_bounds__(256) void k_stats(const float* __restrict__ accL,
                                               const float* __restrict__ accH, int N,
                                               float* __restrict__ sums) {
    int tid = threadIdx.x;
    int f = tid & 127;
    int g = tid >> 7;
    float l1 = 0.f, l2 = 0.f, h1 = 0.f, h2 = 0.f;
    for (int r = blockIdx.x * 2 + g; r < N; r += gridDim.x * 2) {
        float v = accL[(long)r * HIDF + f];
        l1 += v;
        l2 += v * v;
        float u = accH[(long)r * HIDF + f];
        h1 += u;
        h2 += u * u;
    }
    __shared__ float s1[256], s2[256], s3[256], s4[256];
    s1[tid] = l1;
    s2[tid] = l2;
    s3[tid] = h1;
    s4[tid] = h2;
    __syncthreads();
    if (tid < 128) {
        atomicAdd(&sums[f], s1[tid] + s1[tid + 128]);
        atomicAdd(&sums[128 + f], s2[tid] + s2[tid + 128]);
        atomicAdd(&sums[256 + f], s3[tid] + s3[tid + 128]);
        atomicAdd(&sums[384 + f], s4[tid] + s4[tid + 128]);
    }
}

// ---- finalize BN affine for both encoders ----
__global__ void k_bnfin(const float* __restrict__ sums, int N, const float* __restrict__ scale,
                        const float* __restrict__ shift, float* __restrict__ a_mul,
                        float* __restrict__ a_add) {
    int f = threadIdx.x;
    for (int enc = 0; enc < 2; ++enc) {
        float mu = sums[enc * 256 + f] / (float)N;
        float var = sums[enc * 256 + 128 + f] / (float)N - mu * mu;
        float rstd = rsqrtf(var + 1e-5f);
        float am = rstd * scale[f];
        a_mul[enc * 128 + f] = am;
        a_add[enc * 128 + f] = shift[f] - mu * am;
    }
}

// ---- up GEMM with fused BN transform + bias + relu; grid.y selects encoder ----
__global__ __launch_bounds__(256) void k_gemm_up(
    const float* __restrict__ accL, const float* __restrict__ accH,
    const float* __restrict__ W, const float* __restrict__ bias,
    const float* __restrict__ a_mul, const float* __restrict__ a_add,
    float* __restrict__ out, int M) {
    int enc = blockIdx.y;
    const float* A = enc ? accH : accL;
    const float* am = a_mul + enc * 128;
    const float* aa = a_add + enc * 128;
    float* O = out + (size_t)enc * M * 128;
    __shared__ float As[64][17];
    __shared__ float Bs[16][128];
    int tid = threadIdx.x;
    int tx = tid & 31, ty = tid >> 5;
    int row0 = blockIdx.x * 64;
    float acc[8][4] = {};
    for (int k0 = 0; k0 < 128; k0 += 16) {
        for (int l = tid; l < 64 * 16; l += 256) {
            int m = l >> 4, k = l & 15;
            int r = row0 + m;
            float v = (r < M) ? A[(long)r * 128 + k0 + k] : 0.0f;
            As[m][k] = v * am[k0 + k] + aa[k0 + k];
        }
        for (int l = tid; l < 16 * 128; l += 256) {
            int k = l >> 7, n = l & 127;
            Bs[k][n] = W[(long)(k0 + k) * 128 + n];
        }
        __syncthreads();
#pragma unroll
        for (int k = 0; k < 16; ++k) {
            float a[8];
#pragma unroll
            for (int i = 0; i < 8; ++i) a[i] = As[ty * 8 + i][k];
            float4 bb = *(const float4*)&Bs[k][tx * 4];
#pragma unroll
            for (int i = 0; i < 8; ++i) {
                acc[i][0] += a[i] * bb.x;
                acc[i][1] += a[i] * bb.y;
                acc[i][2] += a[i] * bb.z;
                acc[i][3] += a[i] * bb.w;
            }
        }
        __syncthreads();
    }
#pragma unroll
    for (int i = 0; i < 8; ++i) {
        int r = row0 + ty * 8 + i;
        if (r < M) {
#pragma unroll
            for (int j = 0; j < 4; ++j) {
                int n = tx * 4 + j;
                O[(long)r * 128 + n] = fmaxf(acc[i][j] + bias[n], 0.0f);
            }
        }
    }
}

extern "C" void kernel_launch(void* const* d_in, const int* in_sizes, int n_in, void* d_out,
                              int out_size, void* d_ws, size_t ws_size, hipStream_t stream) {
    const float* x = (const float*)d_in[0];
    const int* edge_index = (const int*)d_in[1];
    const float* W_in = (const float*)d_in[2];
    const float* b_in = (const float*)d_in[3];
    const float* gamma_L = (const float*)d_in[4];
    const float* gamma_H = (const float*)d_in[5];
    const float* bn_scale = (const float*)d_in[6];
    const float* bn_shift = (const float*)d_in[7];
    const float* W_up = (const float*)d_in[8];
    const float* b_up = (const float*)d_in[9];
    float* out = (float*)d_out;

    const int HID = in_sizes[3];       // 128
    const int IN = in_sizes[2] / HID;  // 500
    const int N = in_sizes[0] / IN;    // 50000
    const int E = in_sizes[1] / 2;     // 800000
    const int K = in_sizes[4] - 1;     // 10

    const int* src = edge_index;
    const int* dst = edge_index + E;

    // workspace carve-out
    char* p = (char*)d_ws;
    auto alloc = [&](size_t bytes) -> void* {
        void* r = (void*)p;
        p += (bytes + 255) & ~(size_t)255;
        return r;
    };
    int* deg = (int*)alloc((size_t)N * 4);
    int* row_ptr = (int*)alloc((size_t)(N + 1) * 4);
    int* fill = (int*)alloc((size_t)N * 4);
    float* dinv = (float*)alloc((size_t)N * 4);
    int* csr_src = (int*)alloc((size_t)E * 4);
    float* csr_w = (float*)alloc((size_t)E * 4);
    float* h = (float*)alloc((size_t)N * HID * 4);   // doubles as ping-pong buffer
    float* ta = (float*)alloc((size_t)N * HID * 4);
    float* accL = (float*)alloc((size_t)N * HID * 4);
    float* accH = (float*)alloc((size_t)N * HID * 4);
    float* sums = (float*)alloc(512 * 4);
    float* cL = (float*)alloc(64 * 4);
    float* cH = (float*)alloc(64 * 4);
    float* a_mul = (float*)alloc(256 * 4);
    float* a_add = (float*)alloc(256 * 4);

    hipMemsetAsync(deg, 0, (size_t)N * 4, stream);
    hipMemsetAsync(fill, 0, (size_t)N * 4, stream);
    hipMemsetAsync(sums, 0, 512 * 4, stream);

    k_coef<<<1, 64, 0, stream>>>(gamma_L, gamma_H, K, cL, cH);
    k_deg<<<cdiv(E, 256), 256, 0, stream>>>(dst, E, deg);
    k_dinv<<<cdiv(N, 256), 256, 0, stream>>>(deg, N, dinv);
    k_scan<<<1, 1024, 0, stream>>>(deg, N, row_ptr);
    k_scatter<<<cdiv(E, 256), 256, 0, stream>>>(src, dst, E, row_ptr, fill, dinv, csr_src,
                                                csr_w);
    k_gemm_in<<<cdiv(N, 64), 256, 0, stream>>>(x, W_in, b_in, h, accL, accH, cL, cH, N, IN);

    // shared Krylov basis: t_j = P^j h, j=1..K, dual accumulation
    const float* tin = h;
    float* tout = ta;
    for (int j = 1; j <= K; ++j) {
        int write_t = (j < K) ? 1 : 0;
        k_prop<<<cdiv(N, 4), 256, 0, stream>>>(row_ptr, csr_src, csr_w, tin, tout, accL, accH,
                                               cL, cH, j, N, write_t);
        const float* nt = tout;
        tout = (float*)(tin == h ? ta : h);  // ping-pong between h and ta
        // careful: after first swap tout must not alias tin
        tout = (nt == ta) ? h : ta;
        tin = nt;
    }

    k_stats<<<400, 256, 0, stream>>>(accL, accH, N, sums);
    k_bnfin<<<1, 128, 0, stream>>>(sums, N, bn_scale, bn_shift, a_mul, a_add);
    dim3 gup(cdiv(N, 64), 2);
    k_gemm_up<<<gup, 256, 0, stream>>>(accL, accH, W_up, b_up, a_mul, a_add, out, N);
}

// Round 3
// 1192.903 us; speedup vs baseline: 2.0592x; 1.1387x over previous
//
#include <hip/hip_runtime.h>

#define HIDF 128

static inline int cdiv(int a, int b) { return (a + b - 1) / b; }

// ---- degree count over dst ----
__global__ void k_deg(const int* __restrict__ dst, int E, int* __restrict__ deg) {
    int i = blockIdx.x * blockDim.x + threadIdx.x;
    if (i < E) atomicAdd(&deg[dst[i]], 1);
}

// ---- dinv = rsqrt(max(deg,1)) ----
__global__ void k_dinv(const int* __restrict__ deg, int N, float* __restrict__ dinv) {
    int i = blockIdx.x * blockDim.x + threadIdx.x;
    if (i < N) {
        float d = (float)deg[i];
        dinv[i] = rsqrtf(fmaxf(d, 1.0f));
    }
}

// ---- coefficient kernel: cL[j]=gamma_L[j]; cH[j]=(-1)^j sum_{k>=j} gamma_H[k]*C(k,j) ----
__global__ void k_coef(const float* __restrict__ gL, const float* __restrict__ gH, int K,
                       float* __restrict__ cL, float* __restrict__ cH) {
    if (threadIdx.x == 0 && blockIdx.x == 0) {
        for (int j = 0; j <= K; ++j) {
            double s = 0.0;
            double C = 1.0;  // C(j,j)
            for (int k = j; k <= K; ++k) {
                s += (double)gH[k] * C;
                C = C * (double)(k + 1) / (double)(k + 1 - j);  // C(k+1,j)
            }
            cH[j] = (j & 1) ? (float)(-s) : (float)s;
            cL[j] = gL[j];
        }
    }
}

// ---- single-block exclusive scan deg -> row_ptr (N+1 entries) ----
__global__ __launch_bounds__(1024) void k_scan(const int* __restrict__ deg, int N,
                                               int* __restrict__ row_ptr) {
    __shared__ int ls[1024];
    int tid = threadIdx.x;
    int chunk = (N + 1023) / 1024;
    int start = tid * chunk;
    int end = min(start + chunk, N);
    int s = 0;
    for (int i = start; i < end; ++i) s += deg[i];
    ls[tid] = s;
    __syncthreads();
    for (int off = 1; off < 1024; off <<= 1) {
        int v = (tid >= off) ? ls[tid - off] : 0;
        __syncthreads();
        ls[tid] += v;
        __syncthreads();
    }
    int run = ls[tid] - s;  // exclusive prefix
    for (int i = start; i < end; ++i) {
        row_ptr[i] = run;
        run += deg[i];
    }
    if (tid == 1023) row_ptr[N] = run;
}

// ---- scatter edges into CSR (by dst) ----
__global__ void k_scatter(const int* __restrict__ src, const int* __restrict__ dst, int E,
                          const int* __restrict__ row_ptr, int* __restrict__ fill,
                          const float* __restrict__ dinv, int* __restrict__ csr_src,
                          float* __restrict__ csr_w) {
    int i = blockIdx.x * blockDim.x + threadIdx.x;
    if (i < E) {
        int s = src[i], d = dst[i];
        int pos = row_ptr[d] + atomicAdd(&fill[d], 1);
        csr_src[pos] = s;
        csr_w[pos] = dinv[s] * dinv[d];
    }
}

// ---- input GEMM: H = X @ W + b; epilogue: accL = cL0*H, accH = cH0*H ----
// BM=128, BN=128, BK=20, 512 threads, each computes 8x4
// As stored TRANSPOSED [BK][128+4] so A-row reads are ds_read_b128.
__global__ __launch_bounds__(512) void k_gemm_in(
    const float* __restrict__ X, const float* __restrict__ W, const float* __restrict__ b,
    float* __restrict__ H, float* __restrict__ accL, float* __restrict__ accH,
    const float* __restrict__ cL, const float* __restrict__ cH, int M, int Kdim) {
    const int BK = 20;
    __shared__ float As[BK][132];
    __shared__ float Bs[BK][128];
    int tid = threadIdx.x;
    int tx = tid & 31, ty = tid >> 5;  // ty 0..15
    int row0 = blockIdx.x * 128;
    float acc[8][4] = {};
    for (int k0 = 0; k0 < Kdim; k0 += BK) {
        // stage X: 128 rows x 5 float4 = 640 float4 loads
        for (int l = tid; l < 640; l += 512) {
            int m = l / 5, q = l % 5;
            int r = row0 + m;
            float4 v = {0.f, 0.f, 0.f, 0.f};
            if (r < M) v = *(const float4*)&X[(long)r * Kdim + k0 + q * 4];
            As[q * 4 + 0][m] = v.x;
            As[q * 4 + 1][m] = v.y;
            As[q * 4 + 2][m] = v.z;
            As[q * 4 + 3][m] = v.w;
        }
        // stage W: 20x128 = 640 float4
        for (int l = tid; l < 640; l += 512) {
            int k = l >> 5, n = (l & 31) * 4;
            *(float4*)&Bs[k][n] = *(const float4*)&W[(long)(k0 + k) * 128 + n];
        }
        __syncthreads();
#pragma unroll
        for (int k = 0; k < BK; ++k) {
            float4 a0 = *(const float4*)&As[k][ty * 8];
            float4 a1 = *(const float4*)&As[k][ty * 8 + 4];
            float4 bb = *(const float4*)&Bs[k][tx * 4];
            float a[8] = {a0.x, a0.y, a0.z, a0.w, a1.x, a1.y, a1.z, a1.w};
#pragma unroll
            for (int i = 0; i < 8; ++i) {
                acc[i][0] += a[i] * bb.x;
                acc[i][1] += a[i] * bb.y;
                acc[i][2] += a[i] * bb.z;
                acc[i][3] += a[i] * bb.w;
            }
        }
        __syncthreads();
    }
    float g0 = cL[0], h0 = cH[0];
    float4 bias = *(const float4*)&b[tx * 4];
    float bv[4] = {bias.x, bias.y, bias.z, bias.w};
#pragma unroll
    for (int i = 0; i < 8; ++i) {
        int r = row0 + ty * 8 + i;
        if (r < M) {
            long idx = (long)r * 128 + tx * 4;
            float4 vh, vl, vvh;
            float* ph = (float*)&vh;
            float* pl = (float*)&vl;
            float* pH = (float*)&vvh;
#pragma unroll
            for (int j = 0; j < 4; ++j) {
                float v = acc[i][j] + bv[j];
                ph[j] = v;
                pl[j] = g0 * v;
                pH[j] = h0 * v;
            }
            *(float4*)&H[idx] = vh;
            *(float4*)&accL[idx] = vl;
            *(float4*)&accH[idx] = vvh;
        }
    }
}

// ---- prop step j: t_out = P t_in ; accL += cL[j]*t_out ; accH += cH[j]*t_out ----
// one wave per node; half-wave per edge-parity; float4 (4 features) per lane
__global__ __launch_bounds__(256) void k_prop(
    const int* __restrict__ row_ptr, const int* __restrict__ csr_src,
    const float* __restrict__ csr_w, const float* __restrict__ t_in,
    float* __restrict__ t_out, float* __restrict__ accL, float* __restrict__ accH,
    const float* __restrict__ cL, const float* __restrict__ cH, int j, int N, int write_t) {
    int wave = threadIdx.x >> 6;
    int lane = threadIdx.x & 63;
    int half = lane >> 5;   // 0: even edges, 1: odd edges
    int l5 = lane & 31;     // feature group: features l5*4 .. l5*4+3
    int node = blockIdx.x * 4 + wave;
    if (node >= N) return;
    int e0 = row_ptr[node], e1 = row_ptr[node + 1];
    float sx = 0.f, sy = 0.f, sz = 0.f, sw = 0.f;
    int e = e0 + half;
    // unroll 2 (stride 4 per half): up to 4 rows in flight per wave
    for (; e + 2 < e1; e += 4) {
        int i0 = csr_src[e];
        int i1 = csr_src[e + 2];
        float w0 = csr_w[e];
        float w1 = csr_w[e + 2];
        float4 v0 = *(const float4*)&t_in[(long)i0 * HIDF + l5 * 4];
        float4 v1 = *(const float4*)&t_in[(long)i1 * HIDF + l5 * 4];
        sx += w0 * v0.x + w1 * v1.x;
        sy += w0 * v0.y + w1 * v1.y;
        sz += w0 * v0.z + w1 * v1.z;
        sw += w0 * v0.w + w1 * v1.w;
    }
    if (e < e1) {
        int i0 = csr_src[e];
        float w0 = csr_w[e];
        float4 v0 = *(const float4*)&t_in[(long)i0 * HIDF + l5 * 4];
        sx += w0 * v0.x;
        sy += w0 * v0.y;
        sz += w0 * v0.z;
        sw += w0 * v0.w;
    }
    // combine halves: lane l and l+32 hold same features over disjoint edges
    sx += __shfl_xor(sx, 32);
    sy += __shfl_xor(sy, 32);
    sz += __shfl_xor(sz, 32);
    sw += __shfl_xor(sw, 32);
    if (half == 0) {
        long base = (long)node * HIDF + l5 * 4;
        if (write_t) {
            float4 o = {sx, sy, sz, sw};
            *(float4*)&t_out[base] = o;
        }
        float gL = cL[j], gH = cH[j];
        float4 aL = *(const float4*)&accL[base];
        float4 aH = *(const float4*)&accH[base];
        aL.x += gL * sx;
        aL.y += gL * sy;
        aL.z += gL * sz;
        aL.w += gL * sw;
        aH.x += gH * sx;
        aH.y += gH * sy;
        aH.z += gH * sz;
        aH.w += gH * sw;
        *(float4*)&accL[base] = aL;
        *(float4*)&accH[base] = aH;
    }
}

// ---- BN stats for BOTH accs (float4 reads): sums layout
// [0:128) L sum, [128:256) L sumsq, [256:384) H sum, [384:512) H sumsq
__global__ __launch_bounds__(256) void k_stats(const float* __restrict__ accL,
                                               const float* __restrict__ accH, int N,
                                               float* __restrict__ sums) {
    int tid = threadIdx.x;
    int l5 = tid & 31;   // feature group l5*4
    int g = tid >> 5;    // 0..7 row groups
    float4 l1 = {0, 0, 0, 0}, l2 = {0, 0, 0, 0}, h1 = {0, 0, 0, 0}, h2 = {0, 0, 0, 0};
    for (int r = blockIdx.x * 8 + g; r < N; r += gridDim.x * 8) {
        float4 v = *(const float4*)&accL[(long)r * HIDF + l5 * 4];
        l1.x += v.x; l1.y += v.y; l1.z += v.z; l1.w += v.w;
        l2.x += v.x * v.x; l2.y += v.y * v.y; l2.z += v.z * v.z; l2.w += v.w * v.w;
        float4 u = *(const float4*)&accH[(long)r * HIDF + l5 * 4];
        h1.x += u.x; h1.y += u.y; h1.z += u.z; h1.w += u.w;
        h2.x += u.x * u.x; h2.y += u.y * u.y; h2.z += u.z * u.z; h2.w += u.w * u.w;
    }
    __shared__ float4 s1[256], s2[256], s3[256], s4[256];
    s1[tid] = l1;
    s2[tid] = l2;
    s3[tid] = h1;
    s4[tid] = h2;
    __syncthreads();
    if (tid < 32) {
        float4 a = s1[tid], bq = s2[tid], c = s3[tid], d = s4[tid];
        for (int gg = 1; gg < 8; ++gg) {
            float4 t;
            t = s1[gg * 32 + tid]; a.x += t.x; a.y += t.y; a.z += t.z; a.w += t.w;
            t = s2[gg * 32 + tid]; bq.x += t.x; bq.y += t.y; bq.z += t.z; bq.w += t.w;
            t = s3[gg * 32 + tid]; c.x += t.x; c.y += t.y; c.z += t.z; c.w += t.w;
            t = s4[gg * 32 + tid]; d.x += t.x; d.y += t.y; d.z += t.z; d.w += t.w;
        }
        int f = tid * 4;
        atomicAdd(&sums[f + 0], a.x); atomicAdd(&sums[f + 1], a.y);
        atomicAdd(&sums[f + 2], a.z); atomicAdd(&sums[f + 3], a.w);
        atomicAdd(&sums[128 + f + 0], bq.x); atomicAdd(&sums[128 + f + 1], bq.y);
        atomicAdd(&sums[128 + f + 2], bq.z); atomicAdd(&sums[128 + f + 3], bq.w);
        atomicAdd(&sums[256 + f + 0], c.x); atomicAdd(&sums[256 + f + 1], c.y);
        atomicAdd(&sums[256 + f + 2], c.z); atomicAdd(&sums[256 + f + 3], c.w);
        atomicAdd(&sums[384 + f + 0], d.x); atomicAdd(&sums[384 + f + 1], d.y);
        atomicAdd(&sums[384 + f + 2], d.z); atomicAdd(&sums[384 + f + 3], d.w);
    }
}

// ---- finalize BN affine for both encoders ----
__global__ void k_bnfin(const float* __restrict__ sums, int N, const float* __restrict__ scale,
                        const float* __restrict__ shift, float* __restrict__ a_mul,
                        float* __restrict__ a_add) {
    int f = threadIdx.x;
    for (int enc = 0; enc < 2; ++enc) {
        float mu = sums[enc * 256 + f] / (float)N;
        float var = sums[enc * 256 + 128 + f] / (float)N - mu * mu;
        float rstd = rsqrtf(var + 1e-5f);
        float am = rstd * scale[f];
        a_mul[enc * 128 + f] = am;
        a_add[enc * 128 + f] = shift[f] - mu * am;
    }
}

// ---- up GEMM, BN fused at staging, bias+relu epilogue; grid.y = encoder ----
// BM=128, BN=128, BK=16, 512 threads, As transposed [16][132]
__global__ __launch_bounds__(512) void k_gemm_up(
    const float* __restrict__ accL, const float* __restrict__ accH,
    const float* __restrict__ W, const float* __restrict__ bias,
    const float* __restrict__ a_mul, const float* __restrict__ a_add,
    float* __restrict__ out, int M) {
    int enc = blockIdx.y;
    const float* A = enc ? accH : accL;
    float* O = out + (size_t)enc * M * 128;
    __shared__ float As[16][132];
    __shared__ float Bs[16][128];
    __shared__ float ams[128], aas[128];
    int tid = threadIdx.x;
    int tx = tid & 31, ty = tid >> 5;
    int row0 = blockIdx.x * 128;
    if (tid < 128) {
        ams[tid] = a_mul[enc * 128 + tid];
        aas[tid] = a_add[enc * 128 + tid];
    }
    __syncthreads();
    float acc[8][4] = {};
    for (int k0 = 0; k0 < 128; k0 += 16) {
        // stage A: 128 rows x 4 float4 = 512 float4, one per thread
        {
            int m = tid >> 2, q = tid & 3;
            int r = row0 + m;
            float4 v = {0.f, 0.f, 0.f, 0.f};
            if (r < M) v = *(const float4*)&A[(long)r * 128 + k0 + q * 4];
            int kk = q * 4;
            As[kk + 0][m] = v.x * ams[k0 + kk + 0] + aas[k0 + kk + 0];
            As[kk + 1][m] = v.y * ams[k0 + kk + 1] + aas[k0 + kk + 1];
            As[kk + 2][m] = v.z * ams[k0 + kk + 2] + aas[k0 + kk + 2];
            As[kk + 3][m] = v.w * ams[k0 + kk + 3] + aas[k0 + kk + 3];
        }
        // stage W: 16x128 = 512 float4, one per thread
        {
            int k = tid >> 5, n = (tid & 31) * 4;
            *(float4*)&Bs[k][n] = *(const float4*)&W[(long)(k0 + k) * 128 + n];
        }
        __syncthreads();
#pragma unroll
        for (int k = 0; k < 16; ++k) {
            float4 a0 = *(const float4*)&As[k][ty * 8];
            float4 a1 = *(const float4*)&As[k][ty * 8 + 4];
            float4 bb = *(const float4*)&Bs[k][tx * 4];
            float a[8] = {a0.x, a0.y, a0.z, a0.w, a1.x, a1.y, a1.z, a1.w};
#pragma unroll
            for (int i = 0; i < 8; ++i) {
                acc[i][0] += a[i] * bb.x;
                acc[i][1] += a[i] * bb.y;
                acc[i][2] += a[i] * bb.z;
                acc[i][3] += a[i] * bb.w;
            }
        }
        __syncthreads();
    }
    float4 bv = *(const float4*)&bias[tx * 4];
    float bb[4] = {bv.x, bv.y, bv.z, bv.w};
#pragma unroll
    for (int i = 0; i < 8; ++i) {
        int r = row0 + ty * 8 + i;
        if (r < M) {
            float4 o;
            o.x = fmaxf(acc[i][0] + bb[0], 0.0f);
            o.y = fmaxf(acc[i][1] + bb[1], 0.0f);
            o.z = fmaxf(acc[i][2] + bb[2], 0.0f);
            o.w = fmaxf(acc[i][3] + bb[3], 0.0f);
            *(float4*)&O[(long)r * 128 + tx * 4] = o;
        }
    }
}

extern "C" void kernel_launch(void* const* d_in, const int* in_sizes, int n_in, void* d_out,
                              int out_size, void* d_ws, size_t ws_size, hipStream_t stream) {
    const float* x = (const float*)d_in[0];
    const int* edge_index = (const int*)d_in[1];
    const float* W_in = (const float*)d_in[2];
    const float* b_in = (const float*)d_in[3];
    const float* gamma_L = (const float*)d_in[4];
    const float* gamma_H = (const float*)d_in[5];
    const float* bn_scale = (const float*)d_in[6];
    const float* bn_shift = (const float*)d_in[7];
    const float* W_up = (const float*)d_in[8];
    const float* b_up = (const float*)d_in[9];
    float* out = (float*)d_out;

    const int HID = in_sizes[3];       // 128
    const int IN = in_sizes[2] / HID;  // 500
    const int N = in_sizes[0] / IN;    // 50000
    const int E = in_sizes[1] / 2;     // 800000
    const int K = in_sizes[4] - 1;     // 10

    const int* src = edge_index;
    const int* dst = edge_index + E;

    // workspace carve-out
    char* p = (char*)d_ws;
    auto alloc = [&](size_t bytes) -> void* {
        void* r = (void*)p;
        p += (bytes + 255) & ~(size_t)255;
        return r;
    };
    int* deg = (int*)alloc((size_t)N * 4);
    int* row_ptr = (int*)alloc((size_t)(N + 1) * 4);
    int* fill = (int*)alloc((size_t)N * 4);
    float* dinv = (float*)alloc((size_t)N * 4);
    int* csr_src = (int*)alloc((size_t)E * 4);
    float* csr_w = (float*)alloc((size_t)E * 4);
    float* h = (float*)alloc((size_t)N * HID * 4);  // ping-pong buffer A
    float* ta = (float*)alloc((size_t)N * HID * 4); // ping-pong buffer B
    float* accL = (float*)alloc((size_t)N * HID * 4);
    float* accH = (float*)alloc((size_t)N * HID * 4);
    float* sums = (float*)alloc(512 * 4);
    float* cL = (float*)alloc(64 * 4);
    float* cH = (float*)alloc(64 * 4);
    float* a_mul = (float*)alloc(256 * 4);
    float* a_add = (float*)alloc(256 * 4);

    hipMemsetAsync(deg, 0, (size_t)N * 4, stream);
    hipMemsetAsync(fill, 0, (size_t)N * 4, stream);
    hipMemsetAsync(sums, 0, 512 * 4, stream);

    k_coef<<<1, 64, 0, stream>>>(gamma_L, gamma_H, K, cL, cH);
    k_deg<<<cdiv(E, 256), 256, 0, stream>>>(dst, E, deg);
    k_dinv<<<cdiv(N, 256), 256, 0, stream>>>(deg, N, dinv);
    k_scan<<<1, 1024, 0, stream>>>(deg, N, row_ptr);
    k_scatter<<<cdiv(E, 256), 256, 0, stream>>>(src, dst, E, row_ptr, fill, dinv, csr_src,
                                                csr_w);
    k_gemm_in<<<cdiv(N, 128), 512, 0, stream>>>(x, W_in, b_in, h, accL, accH, cL, cH, N, IN);

    // shared Krylov basis: t_j = P^j h, j=1..K, dual accumulation
    const float* tin = h;
    float* tout = ta;
    for (int j = 1; j <= K; ++j) {
        int write_t = (j < K) ? 1 : 0;
        k_prop<<<cdiv(N, 4), 256, 0, stream>>>(row_ptr, csr_src, csr_w, tin, tout, accL, accH,
                                               cL, cH, j, N, write_t);
        const float* nt = tout;
        tout = (nt == ta) ? h : ta;
        tin = nt;
    }

    k_stats<<<200, 256, 0, stream>>>(accL, accH, N, sums);
    k_bnfin<<<1, 128, 0, stream>>>(sums, N, bn_scale, bn_shift, a_mul, a_add);
    dim3 gup(cdiv(N, 128), 2);
    k_gemm_up<<<gup, 512, 0, stream>>>(accL, accH, W_up, b_up, a_mul, a_add, out, N);
}